// Round 2
// 187.949 us; speedup vs baseline: 1.0743x; 1.0743x over previous
//
#include <hip/hip_runtime.h>

typedef unsigned short u16;
typedef unsigned long long u64;
typedef __bf16 bf16x8 __attribute__((ext_vector_type(8)));
typedef float f32x4 __attribute__((ext_vector_type(4)));

__device__ __forceinline__ float b2f(u16 v) {
    return __uint_as_float(((unsigned int)v) << 16);
}
__device__ __forceinline__ u16 f2b(float f) {
    unsigned int u = __float_as_uint(f);
    u += 0x7fffu + ((u >> 16) & 1u);   // RNE
    return (u16)(u >> 16);
}

// async global->LDS, 16B per lane; LDS dest is wave-uniform base + lane*16B.
__device__ __forceinline__ void ld_lds16(const u16* g, u16* l) {
    __builtin_amdgcn_global_load_lds(
        (__attribute__((address_space(1))) void*)(uintptr_t)(const void*)g,
        (__attribute__((address_space(3))) void*)l, 16, 0, 0);
}

// ---------------------------------------------------------------------------
// Fused prologue: three independent jobs in one dispatch (block-role switch).
//   blocks [0,832):      weight pack f32->bf16
//   blocks [832,1344):   knn phase-1 (per-slab best, NO atomics)
//   blocks [1344,3392):  transpose emb1->emb1t, emb2->emb2t (f32 -> bf16)
// ---------------------------------------------------------------------------
#define PREP_PACK_END  832
#define PREP_KNN_END   1344   // 64 ref-slabs x 8 query-blocks
#define PREP_TRANS_END 3392   // 128 n-tiles x 8 f-tiles x 2 sources

__global__ __launch_bounds__(256) void prep_k(
    const float* __restrict__ w1r, const float* __restrict__ w1t,
    const float* __restrict__ w2r, const float* __restrict__ w2t,
    const float* __restrict__ w3r, const float* __restrict__ w3t,
    u16* __restrict__ wdst,
    const float* __restrict__ t1, const float* __restrict__ t2,
    u64* __restrict__ part,
    const float* __restrict__ e1, const float* __restrict__ e2,
    u16* __restrict__ o1, u16* __restrict__ o2)
{
    __shared__ __align__(16) float smem[64 * 65];
    const int bid = blockIdx.x;
    const int t = threadIdx.x;

    if (bid < PREP_PACK_END) {
        // ---- weight pack: [w1r|w1t|w2r|w2t|w3r|w3t] -> bf16 ----
        size_t i = (size_t)bid * 2048 + (size_t)t * 8;
        const float* src; size_t off;
        if (i < 655360)       { src = w1r; off = 0; }
        else if (i < 1310720) { src = w1t; off = 655360; }
        else if (i < 1474560) { src = w2r; off = 1310720; }
        else if (i < 1638400) { src = w2t; off = 1474560; }
        else if (i < 1671168) { src = w3r; off = 1638400; }
        else                  { src = w3t; off = 1671168; }
        const float4 lo = *(const float4*)(src + (i - off));
        const float4 hi = *(const float4*)(src + (i - off) + 4);
        ushort4 o0v, o1v;
        o0v.x = f2b(lo.x); o0v.y = f2b(lo.y); o0v.z = f2b(lo.z); o0v.w = f2b(lo.w);
        o1v.x = f2b(hi.x); o1v.y = f2b(hi.y); o1v.z = f2b(hi.z); o1v.w = f2b(hi.w);
        *(ushort4*)(wdst + i) = o0v;
        *(ushort4*)(wdst + i + 4) = o1v;
    } else if (bid < PREP_KNN_END) {
        // ---- knn phase-1: slab rs (128 refs), query-block qb (1024 queries) ----
        float4* ref = (float4*)smem;
        const int rb = bid - PREP_PACK_END;
        const int rs = rb & 63;
        const int qb = rb >> 6;
        if (t < 128) {
            int i = rs * 128 + t;
            float x = t1[i], y = t1[8192 + i], z = t1[16384 + i];
            float rr = __fadd_rn(__fadd_rn(__fmul_rn(x, x), __fmul_rn(y, y)), __fmul_rn(z, z));
            ref[t] = make_float4(x, y, z, rr);
        }
        __syncthreads();

        float qx[4], qy[4], qz[4], qq[4], bestd[4];
        int besti[4];
        const int q0 = qb * 1024 + t;
#pragma unroll
        for (int j = 0; j < 4; ++j) {
            int q = q0 + j * 256;
            qx[j] = t2[q]; qy[j] = t2[8192 + q]; qz[j] = t2[16384 + q];
            qq[j] = __fadd_rn(__fadd_rn(__fmul_rn(qx[j], qx[j]), __fmul_rn(qy[j], qy[j])),
                              __fmul_rn(qz[j], qz[j]));
            bestd[j] = __uint_as_float(0x7f800000u);
            besti[j] = 0;
        }
        for (int i = 0; i < 128; ++i) {
            float4 r = ref[i];
            int ridx = rs * 128 + i;
#pragma unroll
            for (int j = 0; j < 4; ++j) {
                float g = __fmaf_rn(qz[j], r.z, __fmaf_rn(qy[j], r.y, __fmul_rn(qx[j], r.x)));
                float d2 = __fsub_rn(__fadd_rn(r.w, qq[j]), __fmul_rn(2.0f, g));
                if (d2 < bestd[j]) { bestd[j] = d2; besti[j] = i + rs * 128; }
            }
        }
#pragma unroll
        for (int j = 0; j < 4; ++j) {
            u64 key = ((u64)__float_as_uint(bestd[j]) << 32) | (unsigned int)besti[j];
            part[(size_t)rs * 8192 + q0 + j * 256] = key;
        }
    } else {
        // ---- transpose: z=0 emb1->emb1t, z=1 emb2->emb2t (both stride 512) ----
        float (*tile)[65] = (float(*)[65])smem;
        const int tb = bid - PREP_KNN_END;
        const int z = tb >> 10;
        const int rem = tb & 1023;
        const int fy = rem >> 7;      // 8 f-tiles
        const int nx = rem & 127;     // 128 n-tiles
        const float* in = z ? e2 : e1;
        u16* out = z ? o2 : o1;
        const int n0 = nx * 64, f0 = fy * 64;
        const int c = t & 63, r4 = t >> 6;
#pragma unroll
        for (int p = 0; p < 16; ++p) {
            int fr = p * 4 + r4;
            tile[fr][c] = in[(size_t)(f0 + fr) * 8192 + n0 + c];
        }
        __syncthreads();
        const int fc = (t & 15) * 4;    // f-chunk of 4
        const int nr4 = t >> 4;         // 16 n-rows covered per pass
#pragma unroll
        for (int p = 0; p < 4; ++p) {
            int nr = p * 16 + nr4;
            ushort4 o;
            o.x = f2b(tile[fc + 0][nr]); o.y = f2b(tile[fc + 1][nr]);
            o.z = f2b(tile[fc + 2][nr]); o.w = f2b(tile[fc + 3][nr]);
            *(ushort4*)&out[(size_t)(n0 + nr) * 512 + f0 + fc] = o;
        }
    }
}

// ---------------------------------------------------------------------------
// knn phase-2: min over 64 slabs -> 32-bit ref index per query.
// ---------------------------------------------------------------------------
__global__ __launch_bounds__(256) void knn_reduce_k(
    const u64* __restrict__ part, unsigned int* __restrict__ idx)
{
    const int q = blockIdx.x * 256 + threadIdx.x;
    u64 best = ~0ull;
#pragma unroll
    for (int s = 0; s < 64; ++s) {
        u64 k = part[(size_t)s * 8192 + q];
        best = k < best ? k : best;
    }
    idx[q] = (unsigned int)best;
}

// ---------------------------------------------------------------------------
// Layer 1 GEMM with the gather FUSED into B staging: B row n is
//   k <  512 : emb1t[idx[n]][k]
//   k >= 512 : emb2t[n][k-512]
// global_load_lds sources are per-lane, so the gather is free.
// 128m x 128n tile, BK=32, m97 structure. K=1024 fixed.
// ---------------------------------------------------------------------------
__global__ __launch_bounds__(256) void gemm1_k(
    const u16* __restrict__ Ar, const u16* __restrict__ At,
    const float* __restrict__ biasr, const float* __restrict__ biast,
    const u16* __restrict__ emb1t, const u16* __restrict__ emb2t,
    const unsigned int* __restrict__ idx,
    u16* __restrict__ Ct)                    // h1t, stride 1280
{
    constexpr int K = 1024;
    __shared__ __align__(16) u16 lds_a[128 * 32];
    __shared__ __align__(16) u16 lds_b[128 * 32];

    const int t = threadIdx.x;
    const int n0 = blockIdx.x * 128;
    const int m0 = blockIdx.y * 128;
    const int branch = blockIdx.z;

    const u16* A = branch ? At : Ar;
    const float* bias = branch ? biast : biasr;
    const int out_off = branch * 640;

    const int w = t >> 6, l = t & 63;
    const int sr = l >> 2, sc = (l & 3) * 8;

    const u16* gA0 = A + (size_t)(m0 + w * 32 + sr) * K + sc;
    const u16* gA1 = gA0 + (size_t)16 * K;
    u16* lA0 = &lds_a[w * 1024];
    u16* lA1 = lA0 + 512;

    const int row0 = n0 + w * 32 + sr;
    const int row1 = row0 + 16;
    const unsigned int i0 = idx[row0];
    const unsigned int i1 = idx[row1];
    const u16* gB0 = emb1t + (size_t)i0 * 512 + sc;
    const u16* gB1 = emb1t + (size_t)i1 * 512 + sc;
    u16* lB0 = &lds_b[w * 1024];
    u16* lB1 = lB0 + 512;

    const int wm = (w & 1) * 64;
    const int wn = (w >> 1) * 64;
    const int lrow = l & 15, quad = l >> 4;
    const u16* fa = &lds_a[(wm + lrow) * 32 + quad * 8];
    const u16* fb = &lds_b[(wn + lrow) * 32 + quad * 8];

    f32x4 acc[4][4];
#pragma unroll
    for (int i = 0; i < 4; ++i)
#pragma unroll
        for (int j = 0; j < 4; ++j)
            acc[i][j] = (f32x4){0.f, 0.f, 0.f, 0.f};

    ld_lds16(gA0, lA0); ld_lds16(gA1, lA1);
    ld_lds16(gB0, lB0); ld_lds16(gB1, lB1);

    for (int kt = 0; kt < K; kt += 32) {
        __syncthreads();
        bf16x8 af[4], bfr[4];
#pragma unroll
        for (int i = 0; i < 4; ++i) af[i] = *(const bf16x8*)(fa + i * 16 * 32);
#pragma unroll
        for (int j = 0; j < 4; ++j) bfr[j] = *(const bf16x8*)(fb + j * 16 * 32);
        __syncthreads();
        if (kt + 32 < K) {
            gA0 += 32; gA1 += 32;
            if (kt + 32 == 512) {   // switch B source: emb1 gather -> emb2 direct
                gB0 = emb2t + (size_t)row0 * 512 + sc;
                gB1 = emb2t + (size_t)row1 * 512 + sc;
            } else {
                gB0 += 32; gB1 += 32;
            }
            ld_lds16(gA0, lA0); ld_lds16(gA1, lA1);
            ld_lds16(gB0, lB0); ld_lds16(gB1, lB1);
        }
#pragma unroll
        for (int i = 0; i < 4; ++i)
#pragma unroll
            for (int j = 0; j < 4; ++j)
                acc[i][j] = __builtin_amdgcn_mfma_f32_16x16x32_bf16(
                    af[i], bfr[j], acc[i][j], 0, 0, 0);
    }

    // epilogue: D row m = quad*4+reg, col n = lrow; relu always
#pragma unroll
    for (int i = 0; i < 4; ++i) {
        const int mbase = m0 + wm + i * 16 + quad * 4;
        const float4 bbv = *(const float4*)&bias[mbase];
#pragma unroll
        for (int j = 0; j < 4; ++j) {
            const int n = n0 + wn + j * 16 + lrow;
            f32x4 v = acc[i][j];
            float x0 = fmaxf(v[0] + bbv.x, 0.f);
            float x1 = fmaxf(v[1] + bbv.y, 0.f);
            float x2 = fmaxf(v[2] + bbv.z, 0.f);
            float x3 = fmaxf(v[3] + bbv.w, 0.f);
            ushort4 o;
            o.x = f2b(x0); o.y = f2b(x1); o.z = f2b(x2); o.w = f2b(x3);
            *(ushort4*)&Ct[(size_t)n * 1280 + out_off + mbase] = o;
        }
    }
}

// ---------------------------------------------------------------------------
// GEMM (BT): Ct[n][out_off+m] = act( sum_k A[m][k]*Bt[n][b_off+k] + bias[m] )
// A: bf16 (Mh x K) row-major (pre-packed). Used for layer 2 (TN=64).
// ---------------------------------------------------------------------------
template <int TN>
__global__ __launch_bounds__(256) void gemm_bt(
    const u16* __restrict__ Ar, const u16* __restrict__ At,
    const float* __restrict__ biasr, const float* __restrict__ biast,
    const u16* __restrict__ Bt, u16* __restrict__ Ct,
    int Mh, int K, int bstride, int b_step, int ostride, int relu)
{
    constexpr int NJ = TN / 32;               // 4 or 2
    __shared__ __align__(16) u16 lds_a[128 * 32];
    __shared__ __align__(16) u16 lds_b[TN * 32];

    const int t = threadIdx.x;
    const int n0 = blockIdx.x * TN;
    const int m0 = blockIdx.y * 128;
    const int branch = blockIdx.z;

    const u16* A = branch ? At : Ar;
    const float* bias = branch ? biast : biasr;
    const int b_off = branch * b_step;
    const int out_off = branch * Mh;

    const int w = t >> 6, l = t & 63;
    const int sr = l >> 2, sc = (l & 3) * 8;

    const u16* gA0 = A + (size_t)(m0 + w * 32 + sr) * K + sc;
    const u16* gA1 = gA0 + (size_t)16 * K;
    u16* lA0 = &lds_a[w * 1024];
    u16* lA1 = lA0 + 512;

    const u16* gB0;
    const u16* gB1 = nullptr;
    u16 *lB0, *lB1 = nullptr;
    if (TN == 128) {
        gB0 = Bt + (size_t)(n0 + w * 32 + sr) * bstride + b_off + sc;
        gB1 = gB0 + (size_t)16 * bstride;
        lB0 = &lds_b[w * 1024];
        lB1 = lB0 + 512;
    } else {
        gB0 = Bt + (size_t)(n0 + w * 16 + sr) * bstride + b_off + sc;
        lB0 = &lds_b[w * 512];
    }

    const int wm = (w & 1) * 64;
    const int wn = (w >> 1) * (TN / 2);
    const int lrow = l & 15, quad = l >> 4;
    const u16* fa = &lds_a[(wm + lrow) * 32 + quad * 8];
    const u16* fb = &lds_b[(wn + lrow) * 32 + quad * 8];

    f32x4 acc[4][NJ];
#pragma unroll
    for (int i = 0; i < 4; ++i)
#pragma unroll
        for (int j = 0; j < NJ; ++j)
            acc[i][j] = (f32x4){0.f, 0.f, 0.f, 0.f};

    ld_lds16(gA0, lA0); ld_lds16(gA1, lA1);
    ld_lds16(gB0, lB0);
    if (TN == 128) ld_lds16(gB1, lB1);

    for (int kt = 0; kt < K; kt += 32) {
        __syncthreads();
        bf16x8 af[4], bfr[NJ];
#pragma unroll
        for (int i = 0; i < 4; ++i) af[i] = *(const bf16x8*)(fa + i * 16 * 32);
#pragma unroll
        for (int j = 0; j < NJ; ++j) bfr[j] = *(const bf16x8*)(fb + j * 16 * 32);
        __syncthreads();
        if (kt + 32 < K) {
            gA0 += 32; gA1 += 32; gB0 += 32;
            ld_lds16(gA0, lA0); ld_lds16(gA1, lA1);
            ld_lds16(gB0, lB0);
            if (TN == 128) { gB1 += 32; ld_lds16(gB1, lB1); }
        }
#pragma unroll
        for (int i = 0; i < 4; ++i)
#pragma unroll
            for (int j = 0; j < NJ; ++j)
                acc[i][j] = __builtin_amdgcn_mfma_f32_16x16x32_bf16(
                    af[i], bfr[j], acc[i][j], 0, 0, 0);
    }

    // epilogue: D row m = quad*4+reg, col n = lrow
#pragma unroll
    for (int i = 0; i < 4; ++i) {
        const int mbase = m0 + wm + i * 16 + quad * 4;
        const float4 bbv = *(const float4*)&bias[mbase];
#pragma unroll
        for (int j = 0; j < NJ; ++j) {
            const int n = n0 + wn + j * 16 + lrow;
            f32x4 v = acc[i][j];
            float x0 = v[0] + bbv.x, x1 = v[1] + bbv.y;
            float x2 = v[2] + bbv.z, x3 = v[3] + bbv.w;
            if (relu) {
                x0 = fmaxf(x0, 0.f); x1 = fmaxf(x1, 0.f);
                x2 = fmaxf(x2, 0.f); x3 = fmaxf(x3, 0.f);
            }
            ushort4 o;
            o.x = f2b(x0); o.y = f2b(x1); o.z = f2b(x2); o.w = f2b(x3);
            *(ushort4*)&Ct[(size_t)n * ostride + out_off + mbase] = o;
        }
    }
}

// ---------------------------------------------------------------------------
// Fused layer 3 + layer 4 + slice + transpose + concat.
// Grid (128, 2): 64-n-row tile, branch = blockIdx.y. K=256, full M=128 per
// block -> whole h3 segment lives in this block's acc; layer 4 (7 obj rows)
// computed from f32 h3 in LDS (stride 132: conflict-free), output f32 direct.
// out[0:32768) = rx n*4+k ; out[32768:57344) = tx n*3+k.
// ---------------------------------------------------------------------------
__global__ __launch_bounds__(256) void gemm3_final_k(
    const u16* __restrict__ Ar, const u16* __restrict__ At,
    const float* __restrict__ b3r, const float* __restrict__ b3t,
    const u16* __restrict__ Bt,          // h2t, stride 512
    const float* __restrict__ w4r, const float* __restrict__ b4r,
    const float* __restrict__ w4t, const float* __restrict__ b4t,
    const int* __restrict__ objp, float* __restrict__ out)
{
    __shared__ __align__(16) u16 lds_a[128 * 32];
    __shared__ __align__(16) u16 lds_b[64 * 32];
    __shared__ __align__(16) float lds_h[64 * 132];  // h3 f32, padded stride
    __shared__ __align__(16) float lds_w[4 * 132];   // obj-selected w4 rows

    const int t = threadIdx.x;
    const int n0 = blockIdx.x * 64;
    const int branch = blockIdx.y;

    const u16* A = branch ? At : Ar;
    const float* bias = branch ? b3t : b3r;
    const int b_off = branch * 256;

    const int w = t >> 6, l = t & 63;
    const int sr = l >> 2, sc = (l & 3) * 8;

    const u16* gA0 = A + (size_t)(w * 32 + sr) * 256 + sc;
    const u16* gA1 = gA0 + (size_t)16 * 256;
    u16* lA0 = &lds_a[w * 1024];
    u16* lA1 = lA0 + 512;

    const u16* gB0 = Bt + (size_t)(n0 + w * 16 + sr) * 512 + b_off + sc;
    u16* lB0 = &lds_b[w * 512];

    const int wm = (w & 1) * 64;
    const int wn = (w >> 1) * 32;
    const int lrow = l & 15, quad = l >> 4;
    const u16* fa = &lds_a[(wm + lrow) * 32 + quad * 8];
    const u16* fb = &lds_b[(wn + lrow) * 32 + quad * 8];

    f32x4 acc[4][2];
#pragma unroll
    for (int i = 0; i < 4; ++i)
#pragma unroll
        for (int j = 0; j < 2; ++j)
            acc[i][j] = (f32x4){0.f, 0.f, 0.f, 0.f};

    ld_lds16(gA0, lA0); ld_lds16(gA1, lA1);
    ld_lds16(gB0, lB0);

    for (int kt = 0; kt < 256; kt += 32) {
        __syncthreads();
        bf16x8 af[4], bfr[2];
#pragma unroll
        for (int i = 0; i < 4; ++i) af[i] = *(const bf16x8*)(fa + i * 16 * 32);
#pragma unroll
        for (int j = 0; j < 2; ++j) bfr[j] = *(const bf16x8*)(fb + j * 16 * 32);
        __syncthreads();
        if (kt + 32 < 256) {
            gA0 += 32; gA1 += 32; gB0 += 32;
            ld_lds16(gA0, lA0); ld_lds16(gA1, lA1);
            ld_lds16(gB0, lB0);
        }
#pragma unroll
        for (int i = 0; i < 4; ++i)
#pragma unroll
            for (int j = 0; j < 2; ++j)
                acc[i][j] = __builtin_amdgcn_mfma_f32_16x16x32_bf16(
                    af[i], bfr[j], acc[i][j], 0, 0, 0);
    }

    // ---- h3 (f32, relu) -> LDS ----
#pragma unroll
    for (int i = 0; i < 4; ++i) {
        const int mbase = wm + i * 16 + quad * 4;
        const float4 bbv = *(const float4*)&bias[mbase];
#pragma unroll
        for (int j = 0; j < 2; ++j) {
            const int nl = wn + j * 16 + lrow;
            f32x4 v = acc[i][j];
            float4 x;
            x.x = fmaxf(v[0] + bbv.x, 0.f); x.y = fmaxf(v[1] + bbv.y, 0.f);
            x.z = fmaxf(v[2] + bbv.z, 0.f); x.w = fmaxf(v[3] + bbv.w, 0.f);
            *(float4*)&lds_h[nl * 132 + mbase] = x;
        }
    }
    // ---- obj-selected w4 rows -> LDS ----
    const int o = objp[0];
    const int NR = branch ? 3 : 4;
    const float* w4 = branch ? w4t : w4r;
    if (t < 128) {
        for (int r = 0; r < NR; ++r)
            lds_w[r * 132 + t] = w4[(size_t)(o * NR + r) * 128 + t];
    }
    __syncthreads();

    // ---- layer 4: thread t -> (n_local = t>>2, k = t&3) ----
    const int nl = t >> 2, k = t & 3;
    if (k < NR) {
        const float4* hp = (const float4*)&lds_h[nl * 132];
        const float4* wp4 = (const float4*)&lds_w[k * 132];
        float s = 0.f;
#pragma unroll
        for (int m4 = 0; m4 < 32; ++m4) {
            float4 h = hp[m4], ww = wp4[m4];
            s = fmaf(h.x, ww.x, s); s = fmaf(h.y, ww.y, s);
            s = fmaf(h.z, ww.z, s); s = fmaf(h.w, ww.w, s);
        }
        const int n = n0 + nl;
        if (branch == 0) out[(size_t)n * 4 + k] = s + b4r[o * 4 + k];
        else             out[32768 + (size_t)n * 3 + k] = s + b4t[o * 3 + k];
    }
}

// ---------------------------------------------------------------------------
extern "C" void kernel_launch(void* const* d_in, const int* in_sizes, int n_in,
                              void* d_out, int out_size, void* d_ws, size_t ws_size,
                              hipStream_t stream)
{
    const float* emb1 = (const float*)d_in[0];
    const float* emb2 = (const float*)d_in[1];
    const float* t1   = (const float*)d_in[2];
    const float* t2   = (const float*)d_in[3];
    const int*   obj  = (const int*)d_in[4];
    const float* w1r = (const float*)d_in[5];  const float* b1r = (const float*)d_in[6];
    const float* w2r = (const float*)d_in[7];  const float* b2r = (const float*)d_in[8];
    const float* w3r = (const float*)d_in[9];  const float* b3r = (const float*)d_in[10];
    const float* w4r = (const float*)d_in[11]; const float* b4r = (const float*)d_in[12];
    const float* w1t = (const float*)d_in[13]; const float* b1t = (const float*)d_in[14];
    const float* w2t = (const float*)d_in[15]; const float* b2t = (const float*)d_in[16];
    const float* w3t = (const float*)d_in[17]; const float* b3t = (const float*)d_in[18];
    const float* w4t = (const float*)d_in[19]; const float* b4t = (const float*)d_in[20];

    char* ws = (char*)d_ws;
    unsigned int* idx32 = (unsigned int*)ws;                     // 32 KB
    u64* part  = (u64*)(ws + (1u << 16));                        // 4 MB (64 x 8192 keys)
    u16* emb1t = (u16*)(ws + (8u << 20));                        // 8 MB  (8192x512)
    u16* emb2t = (u16*)(ws + (16u << 20));                       // 8 MB  (8192x512)
    u16* h1t   = (u16*)(ws + (24u << 20));                       // 20 MB (8192x1280)
    u16* wp    = (u16*)(ws + (44u << 20));                       // 3.25 MB packed weights
    u16* h2t   = emb1t;   // reuse after gemm1

    u16* w1rp = wp;            u16* w1tp = wp + 655360;
    u16* w2rp = wp + 1310720;  u16* w2tp = wp + 1474560;
    u16* w3rp = wp + 1638400;  u16* w3tp = wp + 1671168;

    prep_k<<<PREP_TRANS_END, 256, 0, stream>>>(w1r, w1t, w2r, w2t, w3r, w3t, wp,
                                               t1, t2, part,
                                               emb1, emb2, emb1t, emb2t);
    knn_reduce_k<<<32, 256, 0, stream>>>(part, idx32);
    gemm1_k<<<dim3(64, 5, 2), 256, 0, stream>>>(w1rp, w1tp, b1r, b1t,
                                                emb1t, emb2t, idx32, h1t);
    gemm_bt<64><<<dim3(128, 2, 2), 256, 0, stream>>>(w2rp, w2tp, b2r, b2t, h1t, h2t,
                                                     256, 640, 1280, 640, 512, 1);
    gemm3_final_k<<<dim3(128, 2), 256, 0, stream>>>(w3rp, w3tp, b3r, b3t, h2t,
                                                    w4r, b4r, w4t, b4t, obj, (float*)d_out);
}